// Round 8
// baseline (12463.870 us; speedup 1.0000x reference)
//
#include <hip/hip_runtime.h>
#include <stdint.h>

typedef __attribute__((ext_vector_type(8))) short bf16x8;
typedef __attribute__((ext_vector_type(4))) float f32x4;
typedef unsigned short u16;

#define MFMA16(a,b,c) __builtin_amdgcn_mfma_f32_16x16x32_bf16((a),(b),(c),0,0,0)

static constexpr int T_STEPS = 256;
static constexpr int BATCH   = 2048;
static constexpr int YDIM    = 20;
static constexpr int BS      = 16;            // batch rows per WG
static constexpr int NWG     = BATCH / BS;    // 128

// ws: 1504 blocks of 1KB (512 u16), frag-linear (verified R3 layout).
// Block b, lane L (0..63), j (0..7): element = W[row][k], row = rowbase + (L&15),
// k = kb*32 + (L>>4)*8 + j.
// [0,384):    whh0, kb-major (48/kb: g*16+c)
// [384,432):  wih0, K padded 20->32
// [432,448):  zero pad
// [448,1216): L1: per kb {whh1 48 | wih1 48}
// [1216,1344): W1 (per kb 16: c)
// [1344,1472): W2
// [1472,1488): W3 (blk = kb*2+ct, rows pad 20->32)
// [1488,1504): zero pad
static constexpr int NBLK     = 1504;
static constexpr int WS_TOTAL = NBLK * 512;
static constexpr int RING_U16 = 12 * 512;     // 12 blocks (12 KB) per-wave ring

__device__ __forceinline__ u16 f2bf(float x) {
    uint32_t u = __float_as_uint(x);
    u += 0x7FFFu + ((u >> 16) & 1u);
    return (u16)(u >> 16);
}
__device__ __forceinline__ float bf2f(u16 h) {
    return __uint_as_float(((uint32_t)h) << 16);
}
__device__ __forceinline__ float sigm(float x) { return 1.0f / (1.0f + __expf(-x)); }
__device__ __forceinline__ float tanh_fast(float x) {
    float s = __expf(-2.0f * fabsf(x));
    float r = (1.0f - s) / (1.0f + s);
    return copysignf(r, x);
}
__device__ __forceinline__ f32x4 zero4() { f32x4 v = {0.f, 0.f, 0.f, 0.f}; return v; }

// ---- prep (verbatim from verified R3) ----
__global__ void prep_kernel(const float* __restrict__ Wih0, const float* __restrict__ Whh0,
                            const float* __restrict__ Wih1, const float* __restrict__ Whh1,
                            const float* __restrict__ W1,   const float* __restrict__ W2,
                            const float* __restrict__ W3,   u16* __restrict__ ws,
                            float* __restrict__ out) {
    int tid = blockIdx.x * blockDim.x + threadIdx.x;
    if (tid == 0) out[0] = 0.0f;
    int stride = gridDim.x * blockDim.x;
    for (int i = tid; i < WS_TOTAL; i += stride) {
        int b = i >> 9, q = i & 511, lane = q >> 3, j = q & 7;
        int r = lane & 15, k8 = (lane >> 4) * 8 + j;
        float v = 0.0f;
        if (b < 384) {
            int kb = b / 48, r48 = b % 48;
            v = Whh0[(r48 * 16 + r) * 256 + kb * 32 + k8];
        } else if (b < 432) {
            int r48 = b - 384;
            v = (k8 < YDIM) ? Wih0[(r48 * 16 + r) * YDIM + k8] : 0.0f;
        } else if (b < 448) {
            v = 0.0f;
        } else if (b < 1216) {
            int rel = b - 448;
            int kb = rel / 96, sub = rel % 96;
            int h = sub / 48, r48 = sub % 48;
            int off = (r48 * 16 + r) * 256 + kb * 32 + k8;
            v = (h == 0) ? Whh1[off] : Wih1[off];
        } else if (b < 1344) {
            int rel = b - 1216;
            int kb = rel / 16, c = rel % 16;
            v = W1[(c * 16 + r) * 256 + kb * 32 + k8];
        } else if (b < 1472) {
            int rel = b - 1344;
            int kb = rel / 16, c = rel % 16;
            v = W2[(c * 16 + r) * 256 + kb * 32 + k8];
        } else if (b < 1488) {
            int rel = b - 1472;
            int kb = rel / 2, c = rel % 2;
            int row = c * 16 + r;
            v = (row < YDIM) ? W3[row * 256 + kb * 32 + k8] : 0.0f;
        }
        ws[i] = f2bf(v);
    }
}

#define VMW(N) do { asm volatile("s_waitcnt vmcnt(" #N ")" ::: "memory"); \
                    __builtin_amdgcn_sched_barrier(0); } while (0)
#define LGW()  do { asm volatile("s_waitcnt lgkmcnt(0)" ::: "memory");    \
                    __builtin_amdgcn_sched_barrier(0); } while (0)
#define BARX() do { asm volatile("s_waitcnt lgkmcnt(0)" ::: "memory");    \
                    __builtin_amdgcn_sched_barrier(0);                    \
                    __builtin_amdgcn_s_barrier();                         \
                    __builtin_amdgcn_sched_barrier(0); } while (0)

#define AH(S, KT) (*(const bf16x8*)&S[l16][(KT) * 32 + kq8])

// GRU unit: 6 blocks, one A-frag, gates r,z,(n -> HN or XN)
#define U_GRU(WAITN, AFRAG, XN, ISSUE_STMT) do {                          \
    VMW(WAITN);                                                           \
    const int so = parv * 3072; parv ^= 1;                                \
    const bf16x8 a_ = (AFRAG);                                            \
    const bf16x8 b0_ = LDF(so,0), b1_ = LDF(so,1), b2_ = LDF(so,2),       \
                 b3_ = LDF(so,3), b4_ = LDF(so,4), b5_ = LDF(so,5);       \
    LGW(); { ISSUE_STMT; }                                                \
    aR[0] = MFMA16(a_, b0_, aR[0]);  aR[1] = MFMA16(a_, b1_, aR[1]);      \
    aZ[0] = MFMA16(a_, b2_, aZ[0]);  aZ[1] = MFMA16(a_, b3_, aZ[1]);      \
    if (XN) { aXN[0] = MFMA16(a_, b4_, aXN[0]); aXN[1] = MFMA16(a_, b5_, aXN[1]); } \
    else    { aHN[0] = MFMA16(a_, b4_, aHN[0]); aHN[1] = MFMA16(a_, b5_, aHN[1]); } \
} while (0)

// MLP unit, 6 blocks = 3 k-tiles (2 col-tiles each)
#define U_MLP3(WAITN, SARR, KB, ISSUE_STMT) do {                          \
    VMW(WAITN);                                                           \
    const int so = parv * 3072; parv ^= 1;                                \
    const bf16x8 a0_ = AH(SARR, KB), a1_ = AH(SARR, (KB)+1), a2_ = AH(SARR, (KB)+2); \
    const bf16x8 b0_ = LDF(so,0), b1_ = LDF(so,1), b2_ = LDF(so,2),       \
                 b3_ = LDF(so,3), b4_ = LDF(so,4), b5_ = LDF(so,5);       \
    LGW(); { ISSUE_STMT; }                                                \
    d0  = MFMA16(a0_, b0_, d0);  d1v = MFMA16(a0_, b1_, d1v);             \
    d0  = MFMA16(a1_, b2_, d0);  d1v = MFMA16(a1_, b3_, d1v);             \
    d0  = MFMA16(a2_, b4_, d0);  d1v = MFMA16(a2_, b5_, d1v);             \
} while (0)

// MLP unit, 4 blocks = 2 k-tiles
#define U_MLP2(WAITN, SARR, KB, ISSUE_STMT) do {                          \
    VMW(WAITN);                                                           \
    const int so = parv * 3072; parv ^= 1;                                \
    const bf16x8 a0_ = AH(SARR, KB), a1_ = AH(SARR, (KB)+1);              \
    const bf16x8 b0_ = LDF(so,0), b1_ = LDF(so,1), b2_ = LDF(so,2),       \
                 b3_ = LDF(so,3);                                         \
    LGW(); { ISSUE_STMT; }                                                \
    d0  = MFMA16(a0_, b0_, d0);  d1v = MFMA16(a0_, b1_, d1v);             \
    d0  = MFMA16(a1_, b2_, d0);  d1v = MFMA16(a1_, b3_, d1v);             \
} while (0)

__global__ __launch_bounds__(512, 1) void rnn_main(
    const float* __restrict__ data,
    const float* __restrict__ bih0g, const float* __restrict__ bhh0g,
    const float* __restrict__ bih1g, const float* __restrict__ bhh1g,
    const float* __restrict__ b1g,  const float* __restrict__ b2g,
    const float* __restrict__ b3g,
    const u16* __restrict__ ws, float* __restrict__ out)
{
    __shared__ u16 wring[8 * RING_U16];   // 96 KB: per-wave private 12KB rings
    __shared__ u16 sh_h0[16][264];
    __shared__ u16 sh_h1[16][264];
    __shared__ u16 sh_d1[16][264];
    __shared__ u16 sh_d2[16][264];
    __shared__ u16 sh_x[16][40];          // x(t) bf16, K padded to 32
    __shared__ float sh_xf[320];          // x(t+1) f32 (gld_lds dest + loss targets)

    const int tid  = threadIdx.x;
    const int w    = tid >> 6;            // wave 0..7
    const int lane = tid & 63;
    const int l16  = lane & 15;
    const int kq   = lane >> 4;
    const int kq8  = kq * 8;
    const int b0   = blockIdx.x * BS;
    const u16* wsb = ws;
    u16* ring = wring + w * RING_U16;

    auto GLD = [&](int blk, int dstOff) {
        __builtin_amdgcn_global_load_lds(
            (const __attribute__((address_space(1))) void*)(wsb + (size_t)blk * 512 + lane * 8),
            (__attribute__((address_space(3))) void*)(ring + dstOff), 16, 0, 0);
    };
    auto ISS6 = [&](int base, int so) {     // stride-8 block group
        GLD(base, so);        GLD(base + 8,  so + 512);  GLD(base + 16, so + 1024);
        GLD(base + 24, so + 1536); GLD(base + 32, so + 2048); GLD(base + 40, so + 2560);
    };
    auto ISS4 = [&](int base, int so) {
        GLD(base, so);        GLD(base + 8,  so + 512);
        GLD(base + 16, so + 1024); GLD(base + 24, so + 1536);
    };
    auto ISSW3A = [&](int base, int so) {   // 6 blocks stride 2 (W3 kb0..5)
        GLD(base, so);      GLD(base + 2, so + 512);  GLD(base + 4, so + 1024);
        GLD(base + 6, so + 1536); GLD(base + 8, so + 2048); GLD(base + 10, so + 2560);
    };
    auto ISSW3B = [&](int base, int so) {   // 2 blocks stride 2 (W3 kb6,7)
        GLD(base, so); GLD(base + 2, so + 512);
    };
    auto LDF = [&](int so, int i) -> bf16x8 {
        return *(const bf16x8*)(ring + so + i * 512 + lane * 8);
    };

    // ---- init LDS state + x(0) ----
    for (int i = tid; i < 16 * 264; i += 512) { (&sh_h0[0][0])[i] = 0; (&sh_h1[0][0])[i] = 0; }
    for (int i = tid; i < 16 * 40;  i += 512) (&sh_x[0][0])[i] = 0;
    if (tid < BS * YDIM) {
        float xv = data[(size_t)b0 * YDIM + tid];
        sh_xf[tid] = xv;
        sh_x[tid / YDIM][tid % YDIM] = f2bf(xv);
    }

    // ---- biases to registers ----
    float bR0[2], bZ0[2], bXN0[2], bHN0[2];
    float bR1[2], bZ1[2], bXN1[2], bHN1[2];
    float s1r[2], s2r[2];
    #pragma unroll
    for (int jj = 0; jj < 2; ++jj) {
        const int colb = (w + 8 * jj) * 16 + l16;
        bR0[jj]  = bih0g[colb] + bhh0g[colb];
        bZ0[jj]  = bih0g[colb + 256] + bhh0g[colb + 256];
        bXN0[jj] = bih0g[colb + 512];
        bHN0[jj] = bhh0g[colb + 512];
        bR1[jj]  = bih1g[colb] + bhh1g[colb];
        bZ1[jj]  = bih1g[colb + 256] + bhh1g[colb + 256];
        bXN1[jj] = bih1g[colb + 512];
        bHN1[jj] = bhh1g[colb + 512];
        s1r[jj]  = b1g[colb];
        s2r[jj]  = b2g[colb];
    }
    float s3r = 0.0f;
    { const int col = w * 16 + l16; if (w < 2 && col < YDIM) s3r = b3g[col]; }

    f32x4 aR[2], aZ[2], aXN[2], aHN[2];
    f32x4 d0, d1v;
    auto zeroAcc = [&]() {
        #pragma unroll
        for (int jj = 0; jj < 2; ++jj) { aR[jj] = zero4(); aZ[jj] = zero4(); aXN[jj] = zero4(); aHN[jj] = zero4(); }
    };
    auto combine = [&](u16 (*H)[264], const float* cbR, const float* cbZ,
                       const float* cbXN, const float* cbHN) {
        #pragma unroll
        for (int jj = 0; jj < 2; ++jj) {
            const int colb = (w + 8 * jj) * 16 + l16;
            #pragma unroll
            for (int q = 0; q < 4; ++q) {
                const int row = kq * 4 + q;
                const float r = sigm(aR[jj][q] + cbR[jj]);
                const float z = sigm(aZ[jj][q] + cbZ[jj]);
                const float n = tanh_fast(aXN[jj][q] + cbXN[jj] + r * (aHN[jj][q] + cbHN[jj]));
                const float hp = bf2f(H[row][colb]);
                H[row][colb] = f2bf((1.0f - z) * n + z * hp);
            }
        }
    };

    __syncthreads();   // pre-pipeline: full drain OK

    // prologue: issue u0 (gh0 kb0) -> slot 0, u1 (gh0 kb1) -> slot 1
    ISS6(0 + w, 0);
    ISS6(48 + w, 3072);
    int parv = 0;
    float loss = 0.0f;

    #pragma unroll 1
    for (int t = 0; t < T_STEPS - 1; ++t) {
        // ======== gh0 (u0..u7) + gx0 (u8) ========
        zeroAcc();
        U_GRU(6, AH(sh_h0, 0), 0, ISS6( 96 + w, so));   // u0 -> issues u2
        U_GRU(6, AH(sh_h0, 1), 0, ISS6(144 + w, so));
        U_GRU(6, AH(sh_h0, 2), 0, ISS6(192 + w, so));
        U_GRU(6, AH(sh_h0, 3), 0, ISS6(240 + w, so));
        U_GRU(6, AH(sh_h0, 4), 0, ISS6(288 + w, so));
        U_GRU(6, AH(sh_h0, 5), 0, ISS6(336 + w, so));
        U_GRU(6, AH(sh_h0, 6), 0, ISS6(384 + w, so));   // -> u8 (gx0)
        U_GRU(6, AH(sh_h0, 7), 0, ISS6(448 + w, so));   // -> u9 (whh1 kb0)
        U_GRU(6, (*(const bf16x8*)&sh_x[l16][kq8]), 1, ISS6(496 + w, so)); // u8 -> u10
        BARX();                                          // B1: gh0/gx0 reads done
        combine(sh_h0, bR0, bZ0, bXN0, bHN0);            // h0(new)
        BARX();                                          // B2
        // ======== L1 (u9..u24): per kb {whh1 | wih1} ========
        zeroAcc();
        {   // u9: whh1 kb0 + x(t+1) injection (wave 0)
            VMW(6);
            const int so = parv * 3072; parv ^= 1;
            const bf16x8 a_ = AH(sh_h1, 0);
            const bf16x8 b0_ = LDF(so,0), b1_ = LDF(so,1), b2_ = LDF(so,2),
                         b3_ = LDF(so,3), b4_ = LDF(so,4), b5_ = LDF(so,5);
            LGW();
            if (w == 0) {
                const float* xp = data + (size_t)(t + 1) * (BATCH * YDIM) + (size_t)b0 * YDIM;
                __builtin_amdgcn_global_load_lds(
                    (const __attribute__((address_space(1))) void*)(xp + lane * 4),
                    (__attribute__((address_space(3))) void*)(sh_xf), 16, 0, 0);
                __builtin_amdgcn_global_load_lds(
                    (const __attribute__((address_space(1))) void*)(xp + 64 + lane * 4),
                    (__attribute__((address_space(3))) void*)(sh_xf + 64), 16, 0, 0);
            }
            ISS6(544 + w, so);                           // -> u11 (whh1 kb1)
            aR[0] = MFMA16(a_, b0_, aR[0]);  aR[1] = MFMA16(a_, b1_, aR[1]);
            aZ[0] = MFMA16(a_, b2_, aZ[0]);  aZ[1] = MFMA16(a_, b3_, aZ[1]);
            aHN[0] = MFMA16(a_, b4_, aHN[0]); aHN[1] = MFMA16(a_, b5_, aHN[1]);
        }
        U_GRU(6, AH(sh_h0, 0), 1, ISS6( 592 + w, so));   // u10 -> u12
        U_GRU(6, AH(sh_h1, 1), 0, ISS6( 640 + w, so));
        U_GRU(6, AH(sh_h0, 1), 1, ISS6( 688 + w, so));
        U_GRU(6, AH(sh_h1, 2), 0, ISS6( 736 + w, so));
        U_GRU(6, AH(sh_h0, 2), 1, ISS6( 784 + w, so));
        U_GRU(6, AH(sh_h1, 3), 0, ISS6( 832 + w, so));
        U_GRU(6, AH(sh_h0, 3), 1, ISS6( 880 + w, so));
        U_GRU(6, AH(sh_h1, 4), 0, ISS6( 928 + w, so));
        U_GRU(6, AH(sh_h0, 4), 1, ISS6( 976 + w, so));
        U_GRU(6, AH(sh_h1, 5), 0, ISS6(1024 + w, so));
        U_GRU(6, AH(sh_h0, 5), 1, ISS6(1072 + w, so));
        U_GRU(6, AH(sh_h1, 6), 0, ISS6(1120 + w, so));
        U_GRU(6, AH(sh_h0, 6), 1, ISS6(1168 + w, so));
        U_GRU(6, AH(sh_h1, 7), 0, ISS6(1216 + w, so));   // u23 -> u25 (W1a)
        U_GRU(6, AH(sh_h0, 7), 1, ISS6(1264 + w, so));   // u24 -> u26 (W1b)
        BARX();                                          // B3
        combine(sh_h1, bR1, bZ1, bXN1, bHN1);            // h1(new)
        if (tid < BS * YDIM) {                           // x(t+1): f32 -> bf16 padded
            float xv = sh_xf[tid];
            sh_x[tid / YDIM][tid % YDIM] = f2bf(xv);
        }
        BARX();                                          // B4
        // ======== W1 (u25..u27): d1 = relu(h1 @ W1^T + b1) ========
        d0 = zero4(); d1v = zero4();
        U_MLP3(6, sh_h1, 0, ISS4(1312 + w, so));         // u25 -> u27
        U_MLP3(4, sh_h1, 3, ISS6(1344 + w, so));         // u26 -> u28
        U_MLP2(6, sh_h1, 6, ISS6(1392 + w, so));         // u27 -> u29
        {
            const int c0 = w * 16 + l16, c1 = (8 + w) * 16 + l16;
            #pragma unroll
            for (int q = 0; q < 4; ++q) {
                sh_d1[kq * 4 + q][c0] = f2bf(fmaxf(d0[q]  + s1r[0], 0.0f));
                sh_d1[kq * 4 + q][c1] = f2bf(fmaxf(d1v[q] + s1r[1], 0.0f));
            }
        }
        BARX();                                          // B5
        // ======== W2 (u28..u30): d2 = relu(d1 @ W2^T + b2) ========
        d0 = zero4(); d1v = zero4();
        U_MLP3(6, sh_d1, 0, ISS4(1440 + w, so));         // u28 -> u30
        U_MLP3(4, sh_d1, 3,
               if (w < 2) { ISSW3A(1472 + w, so); } else { ISS6(0 + w, so); });   // u29 -> u31 | u0'
        U_MLP2(6, sh_d1, 6,
               if (w < 2) { ISSW3B(1484 + w, so); } else { ISS6(48 + w, so); });  // u30 -> u32 | u1'
        {
            const int c0 = w * 16 + l16, c1 = (8 + w) * 16 + l16;
            #pragma unroll
            for (int q = 0; q < 4; ++q) {
                sh_d2[kq * 4 + q][c0] = f2bf(fmaxf(d0[q]  + s2r[0], 0.0f));
                sh_d2[kq * 4 + q][c1] = f2bf(fmaxf(d1v[q] + s2r[1], 0.0f));
            }
        }
        BARX();                                          // B6
        // ======== W3 + loss (waves 0,1; u31,u32) ========
        if (w < 2) {
            f32x4 lacc = zero4();
            {   // u31 (6 blocks, W3 kb0..5)
                VMW(2);
                const int so = parv * 3072; parv ^= 1;
                const bf16x8 b0_ = LDF(so,0), b1_ = LDF(so,1), b2_ = LDF(so,2),
                             b3_ = LDF(so,3), b4_ = LDF(so,4), b5_ = LDF(so,5);
                LGW(); ISS6(0 + w, so);                  // -> u0'
                lacc = MFMA16(AH(sh_d2, 0), b0_, lacc);
                lacc = MFMA16(AH(sh_d2, 1), b1_, lacc);
                lacc = MFMA16(AH(sh_d2, 2), b2_, lacc);
                lacc = MFMA16(AH(sh_d2, 3), b3_, lacc);
                lacc = MFMA16(AH(sh_d2, 4), b4_, lacc);
                lacc = MFMA16(AH(sh_d2, 5), b5_, lacc);
            }
            {   // u32 (2 blocks, W3 kb6,7)
                VMW(6);
                const int so = parv * 3072; parv ^= 1;
                const bf16x8 b0_ = LDF(so,0), b1_ = LDF(so,1);
                LGW(); ISS6(48 + w, so);                 // -> u1'
                lacc = MFMA16(AH(sh_d2, 6), b0_, lacc);
                lacc = MFMA16(AH(sh_d2, 7), b1_, lacc);
            }
            const int col = w * 16 + l16;
            if (col < YDIM) {
                #pragma unroll
                for (int q = 0; q < 4; ++q) {
                    const int row = kq * 4 + q;
                    const float e = (lacc[q] + s3r) - sh_xf[row * 20 + col];
                    loss += e * e;
                }
            }
        }
        // waves 2..7 proceed directly into step t+1 (blocked at B1 until 0,1 catch up)
    }

    #pragma unroll
    for (int s = 32; s > 0; s >>= 1) loss += __shfl_down(loss, s, 64);
    if (lane == 0 && w < 2) atomicAdd(out, loss);
}

extern "C" void kernel_launch(void* const* d_in, const int* in_sizes, int n_in,
                              void* d_out, int out_size, void* d_ws, size_t ws_size,
                              hipStream_t stream) {
    const float* data = (const float*)d_in[0];
    const float* Wih0 = (const float*)d_in[1];
    const float* Whh0 = (const float*)d_in[2];
    const float* bih0 = (const float*)d_in[3];
    const float* bhh0 = (const float*)d_in[4];
    const float* Wih1 = (const float*)d_in[5];
    const float* Whh1 = (const float*)d_in[6];
    const float* bih1 = (const float*)d_in[7];
    const float* bhh1 = (const float*)d_in[8];
    const float* W1   = (const float*)d_in[9];
    const float* b1   = (const float*)d_in[10];
    const float* W2   = (const float*)d_in[11];
    const float* b2   = (const float*)d_in[12];
    const float* W3   = (const float*)d_in[13];
    const float* b3   = (const float*)d_in[14];
    u16*   ws  = (u16*)d_ws;
    float* out = (float*)d_out;

    hipLaunchKernelGGL(prep_kernel, dim3(512), dim3(256), 0, stream,
                       Wih0, Whh0, Wih1, Whh1, W1, W2, W3, ws, out);
    hipLaunchKernelGGL(rnn_main, dim3(NWG), dim3(512), 0, stream,
                       data, bih0, bhh0, bih1, bhh1, b1, b2, b3, ws, out);
}

// Round 9
// 4569.924 us; speedup vs baseline: 2.7274x; 2.7274x over previous
//
#include <hip/hip_runtime.h>
#include <stdint.h>

typedef __attribute__((ext_vector_type(4))) float f32x4;
typedef __attribute__((ext_vector_type(2))) long lx2;
typedef unsigned short u16;
typedef unsigned char u8;

#define MFMA8(a,b,c) __builtin_amdgcn_mfma_f32_16x16x32_fp8_fp8((a),(b),(c),0,0,0)
#define AS1(p) ((const __attribute__((address_space(1))) void*)(p))
#define AS3(p) ((__attribute__((address_space(3))) void*)(p))

static constexpr int T_STEPS = 256;
static constexpr int BATCH   = 2048;
static constexpr int YDIM    = 20;
static constexpr int BS      = 16;
static constexpr int NWG     = BATCH / BS;        // 128
// fp8 stream: 768 pairs x 1KB = 24 chunks x 32KB. Pair P, lane L, half h, j:
// byte = P*1024 + L*16 + h*8 + j holds W[row][k] fp8, k = kb*32 + (L>>4)*8 + j,
// col-tile c = wv + 8*h. Pair order (wv = pair%8 = consuming wave):
//  [0,192):   whh0  P = kb*24 + g*8 + wv
//  [192,224): wih0  P = 192 + g*8 + wv (24) + 8 pad
//  [224,416): whh1  P = 224 + kb*24 + g*8 + wv
//  [416,608): wih1
//  [608,672): W1    P = 608 + kb*8 + wv
//  [672,736): W2
//  [736,744): W3    P = 736 + kp*2 + ct   (frags kb=2kp,2kp+1; rows pad 20->32)
//  [744,768): pad
static constexpr int NPAIR   = 768;
static constexpr int WS_U16  = NPAIR * 512;       // 393216 u16 = 768 KB

__device__ __forceinline__ float sigm(float x) { return 1.0f / (1.0f + __expf(-x)); }
__device__ __forceinline__ float tanh_fast(float x) {
    float s = __expf(-2.0f * fabsf(x));
    float r = (1.0f - s) / (1.0f + s);
    return copysignf(r, x);
}
__device__ __forceinline__ f32x4 zero4() { f32x4 v = {0.f,0.f,0.f,0.f}; return v; }
__device__ __forceinline__ u8 f2f8(float v) {
    return (u8)(__builtin_amdgcn_cvt_pk_fp8_f32(v, v, 0, false) & 0xff);
}

__device__ float sval(int P, int half, int l16, int k8,
                      const float* __restrict__ Wih0, const float* __restrict__ Whh0,
                      const float* __restrict__ Wih1, const float* __restrict__ Whh1,
                      const float* __restrict__ W1,   const float* __restrict__ W2,
                      const float* __restrict__ W3) {
    if (P < 192) { int kb=P/24, r=P%24, g=r>>3, wv=r&7, c=wv+8*half;
        return Whh0[(g*256 + c*16 + l16)*256 + kb*32 + k8]; }
    if (P < 224) { int r=P-192; if (r>=24) return 0.f;
        int g=r>>3, wv=r&7, c=wv+8*half, row=g*256+c*16+l16;
        return (k8 < YDIM) ? Wih0[row*YDIM + k8] : 0.f; }
    if (P < 416) { int r=P-224, kb=r/24, rr=r%24, g=rr>>3, wv=rr&7, c=wv+8*half;
        return Whh1[(g*256 + c*16 + l16)*256 + kb*32 + k8]; }
    if (P < 608) { int r=P-416, kb=r/24, rr=r%24, g=rr>>3, wv=rr&7, c=wv+8*half;
        return Wih1[(g*256 + c*16 + l16)*256 + kb*32 + k8]; }
    if (P < 672) { int r=P-608, kb=r>>3, wv=r&7, row=(wv+8*half)*16+l16;
        return W1[row*256 + kb*32 + k8]; }
    if (P < 736) { int r=P-672, kb=r>>3, wv=r&7, row=(wv+8*half)*16+l16;
        return W2[row*256 + kb*32 + k8]; }
    if (P < 744) { int r=P-736, kp=r>>1, ct=r&1, kb=2*kp+half, row=ct*16+l16;
        return (row < YDIM) ? W3[row*256 + kb*32 + k8] : 0.f; }
    return 0.f;
}

__global__ void prep_kernel(const float* __restrict__ Wih0, const float* __restrict__ Whh0,
                            const float* __restrict__ Wih1, const float* __restrict__ Whh1,
                            const float* __restrict__ W1,   const float* __restrict__ W2,
                            const float* __restrict__ W3,   u16* __restrict__ ws,
                            float* __restrict__ out) {
    int tid = blockIdx.x * blockDim.x + threadIdx.x;
    if (tid == 0) out[0] = 0.0f;
    int stride = gridDim.x * blockDim.x;
    for (int m = tid; m < WS_U16; m += stride) {
        int byte0 = 2 * m;
        int P = byte0 >> 10, rem = byte0 & 1023;
        int L = rem >> 4, half = (rem >> 3) & 1, j0 = rem & 7;
        int l16 = L & 15, kqb = (L >> 4) * 8;
        float v0 = sval(P, half, l16, kqb + j0,     Wih0, Whh0, Wih1, Whh1, W1, W2, W3);
        float v1 = sval(P, half, l16, kqb + j0 + 1, Wih0, Whh0, Wih1, Whh1, W1, W2, W3);
        ws[m] = (u16)(__builtin_amdgcn_cvt_pk_fp8_f32(v0, v1, 0, false) & 0xffff);
    }
}

#define TOP(VMN) do {                                               \
    asm volatile("s_waitcnt lgkmcnt(0)" ::: "memory");              \
    __builtin_amdgcn_sched_barrier(0);                              \
    __builtin_amdgcn_s_barrier();                                   \
    __builtin_amdgcn_sched_barrier(0);                              \
    issueOne();                                                     \
    asm volatile("s_waitcnt vmcnt(" #VMN ")" ::: "memory");         \
    __builtin_amdgcn_sched_barrier(0);                              \
} while (0)

#define PAIRV(CSB, P) (*(const lx2*)&ring[(CSB) + (P) * 1024 + lane * 16])
#define AF(S, KT)     (*(const long*)&(S)[l16][(KT) * 32 + kq8])
#define GM2(ACC, A, PV) do { ACC[0] = MFMA8((A), (PV).x, ACC[0]); \
                             ACC[1] = MFMA8((A), (PV).y, ACC[1]); } while (0)
// gate-chunk patterns (4 subgroups = (kb,gate) at sg = kb*3+g)
#define CH_A(CSB, S, KB, AN) do {                                                       \
    const long a0_ = AF(S, KB), a1_ = AF(S, (KB)+1);                                    \
    const lx2 p0_=PAIRV(CSB,w), p1_=PAIRV(CSB,8+w), p2_=PAIRV(CSB,16+w), p3_=PAIRV(CSB,24+w); \
    GM2(aR, a0_, p0_); GM2(aZ, a0_, p1_); GM2(AN, a0_, p2_); GM2(aR, a1_, p3_);         \
} while (0)
#define CH_B(CSB, S, KB, AN) do {                                                       \
    const long a0_ = AF(S, KB), a1_ = AF(S, (KB)+1);                                    \
    const lx2 p0_=PAIRV(CSB,w), p1_=PAIRV(CSB,8+w), p2_=PAIRV(CSB,16+w), p3_=PAIRV(CSB,24+w); \
    GM2(aZ, a0_, p0_); GM2(AN, a0_, p1_); GM2(aR, a1_, p2_); GM2(aZ, a1_, p3_);         \
} while (0)
#define CH_C(CSB, S, KB, AN) do {                                                       \
    const long a0_ = AF(S, KB), a1_ = AF(S, (KB)+1);                                    \
    const lx2 p0_=PAIRV(CSB,w), p1_=PAIRV(CSB,8+w), p2_=PAIRV(CSB,16+w), p3_=PAIRV(CSB,24+w); \
    GM2(AN, a0_, p0_); GM2(aR, a1_, p1_); GM2(aZ, a1_, p2_); GM2(AN, a1_, p3_);         \
} while (0)
#define CH_M(CSB, S, KB0) do {                                                          \
    _Pragma("unroll") for (int s_ = 0; s_ < 4; ++s_) {                                  \
        const long a_ = AF(S, (KB0) + s_); const lx2 p_ = PAIRV(CSB, s_ * 8 + w);       \
        d0 = MFMA8(a_, p_.x, d0); d1v = MFMA8(a_, p_.y, d1v); }                         \
} while (0)
#define ZGRU() do { aR[0]=zero4(); aR[1]=zero4(); aZ[0]=zero4(); aZ[1]=zero4();         \
    aXN[0]=zero4(); aXN[1]=zero4(); aHN[0]=zero4(); aHN[1]=zero4(); } while (0)
#define COMBINE(HSH, HR, BR, BZ, BXN, BHN) do {                                         \
    _Pragma("unroll") for (int jj = 0; jj < 2; ++jj) {                                  \
        const int colb_ = (w + 8 * jj) * 16 + l16;                                      \
        _Pragma("unroll") for (int q = 0; q < 4; ++q) {                                 \
            const float r_ = sigm(aR[jj][q] + BR[jj]);                                  \
            const float z_ = sigm(aZ[jj][q] + BZ[jj]);                                  \
            const float n_ = tanh_fast(aXN[jj][q] + BXN[jj] + r_ * (aHN[jj][q] + BHN[jj])); \
            const float hn_ = (1.0f - z_) * n_ + z_ * HR[jj][q];                        \
            HR[jj][q] = hn_;                                                            \
            HSH[kq * 4 + q][colb_] = f2f8(hn_); } }                                     \
} while (0)
#define DWRITE(DSH, SB) do {                                                            \
    _Pragma("unroll") for (int q = 0; q < 4; ++q) {                                     \
        DSH[kq * 4 + q][w * 16 + l16]       = f2f8(fmaxf(d0[q]  + SB[0], 0.f));         \
        DSH[kq * 4 + q][(8 + w) * 16 + l16] = f2f8(fmaxf(d1v[q] + SB[1], 0.f)); }       \
} while (0)

__global__ __launch_bounds__(512, 1) void rnn_main(
    const float* __restrict__ data,
    const float* __restrict__ bih0g, const float* __restrict__ bhh0g,
    const float* __restrict__ bih1g, const float* __restrict__ bhh1g,
    const float* __restrict__ b1g,  const float* __restrict__ b2g,
    const float* __restrict__ b3g,
    const u16* __restrict__ ws, float* __restrict__ out)
{
    __shared__ __align__(16) u8 ring[4 * 32768];   // 128 KB chunk ring
    __shared__ __align__(16) u8 sh_h0[16][272];    // fp8 matmul-input copies
    __shared__ __align__(16) u8 sh_h1[16][272];
    __shared__ __align__(16) u8 sh_d1[16][272];
    __shared__ __align__(16) u8 sh_d2[16][272];
    __shared__ __align__(16) u8 sh_x[16][32];
    __shared__ __align__(16) float sh_xf[512];     // x(t+1) f32 (loss targets + next x)

    const int tid  = threadIdx.x;
    const int w    = tid >> 6;
    const int lane = tid & 63;
    const int l16  = lane & 15;
    const int kq   = lane >> 4;
    const int kq8  = kq * 8;
    const int b0   = blockIdx.x * BS;
    const int xr   = tid / YDIM, xc = tid - xr * YDIM;

    // init LDS
    for (int i = tid; i < 16 * 272; i += 512) { (&sh_h0[0][0])[i] = 0; (&sh_h1[0][0])[i] = 0; }
    for (int i = tid; i < 16 * 32;  i += 512) (&sh_x[0][0])[i] = 0;
    if (tid < BS * YDIM) sh_x[xr][xc] = f2f8(data[(size_t)b0 * YDIM + tid]);

    // biases -> registers
    float bR0[2], bZ0[2], bXN0[2], bHN0[2], bR1[2], bZ1[2], bXN1[2], bHN1[2], s1r[2], s2r[2];
    #pragma unroll
    for (int jj = 0; jj < 2; ++jj) {
        const int colb = (w + 8 * jj) * 16 + l16;
        bR0[jj]  = bih0g[colb] + bhh0g[colb];
        bZ0[jj]  = bih0g[colb + 256] + bhh0g[colb + 256];
        bXN0[jj] = bih0g[colb + 512];  bHN0[jj] = bhh0g[colb + 512];
        bR1[jj]  = bih1g[colb] + bhh1g[colb];
        bZ1[jj]  = bih1g[colb + 256] + bhh1g[colb + 256];
        bXN1[jj] = bih1g[colb + 512];  bHN1[jj] = bhh1g[colb + 512];
        s1r[jj]  = b1g[colb];  s2r[jj] = b2g[colb];
    }
    float s3r = 0.0f;
    { const int col = w * 16 + l16; if (w < 2 && col < YDIM) s3r = b3g[col]; }

    float hr0[2][4] = {{0,0,0,0},{0,0,0,0}};   // f32 carried state (lane-owned)
    float hr1[2][4] = {{0,0,0,0},{0,0,0,0}};
    f32x4 aR[2], aZ[2], aXN[2], aHN[2], d0, d1v;

    int issPtr = 0, issBuf = 0;
    auto issueOne = [&]() {
        const u8* src = (const u8*)ws + (size_t)issPtr * 32768;
        u8* dst = ring + issBuf * 32768;
        #pragma unroll
        for (int k = 0; k < 4; ++k)
            __builtin_amdgcn_global_load_lds(AS1(src + k * 8192 + tid * 16),
                                             AS3(dst + k * 8192 + tid * 16), 16, 0, 0);
        issPtr = (issPtr == 23) ? 0 : issPtr + 1;
        issBuf = (issBuf + 1) & 3;
    };

    __syncthreads();
    issueOne(); issueOne();        // prime c0, c1
    float loss = 0.0f;

    #pragma unroll 1
    for (int t = 0; t < T_STEPS - 1; ++t) {
        ZGRU();
        // -------- gh0: chunks 0-5 (A = sh_h0 old) --------
        TOP(8); CH_A(0,      sh_h0, 0, aHN);
        TOP(8); CH_B(32768,  sh_h0, 1, aHN);
        TOP(8); CH_C(65536,  sh_h0, 2, aHN);
        TOP(8); CH_A(98304,  sh_h0, 4, aHN);
        TOP(8); CH_B(0,      sh_h0, 5, aHN);
        TOP(8); CH_C(32768,  sh_h0, 6, aHN);
        // -------- gx0: chunk 6 --------
        TOP(8);
        {
            const long ax = *(const long*)&sh_x[l16][kq8];
            const lx2 p0 = PAIRV(65536, w), p1 = PAIRV(65536, 8 + w), p2 = PAIRV(65536, 16 + w);
            GM2(aR, ax, p0); GM2(aZ, ax, p1); GM2(aXN, ax, p2);
        }
        COMBINE(sh_h0, hr0, bR0, bZ0, bXN0, bHN0);      // h0 new (published at next TOP)
        ZGRU();
        // -------- whh1: chunks 7-12 (A = sh_h1 old) --------
        TOP(8); CH_A(98304, sh_h1, 0, aHN);
        TOP(8); CH_B(0,     sh_h1, 1, aHN);
        TOP(8); CH_C(32768, sh_h1, 2, aHN);
        TOP(8); CH_A(65536, sh_h1, 4, aHN);
        TOP(8); CH_B(98304, sh_h1, 5, aHN);
        TOP(8); CH_C(0,     sh_h1, 6, aHN);
        // -------- wih1: chunks 13-18 (A = sh_h0 NEW) --------
        TOP(8); CH_A(32768, sh_h0, 0, aXN);
        TOP(8); CH_B(65536, sh_h0, 1, aXN);
        TOP(8); CH_C(98304, sh_h0, 2, aXN);
        TOP(8); CH_A(0,     sh_h0, 4, aXN);
        TOP(8); CH_B(32768, sh_h0, 5, aXN);
        TOP(8); CH_C(65536, sh_h0, 6, aXN);
        COMBINE(sh_h1, hr1, bR1, bZ1, bXN1, bHN1);      // h1 new
        // -------- W1: chunks 19-20 --------
        d0 = zero4(); d1v = zero4();
        TOP(8); CH_M(98304, sh_h1, 0);
        {   // chunk 20 top: + x(t+1) prefetch (all waves, keeps vmcnt uniform)
            asm volatile("s_waitcnt lgkmcnt(0)" ::: "memory");
            __builtin_amdgcn_sched_barrier(0);
            __builtin_amdgcn_s_barrier();
            __builtin_amdgcn_sched_barrier(0);
            const float* xp = data + (size_t)(t + 1) * (BATCH * YDIM) + (size_t)b0 * YDIM;
            __builtin_amdgcn_global_load_lds(AS1(xp + lane * 4), AS3(sh_xf), 16, 0, 0);
            __builtin_amdgcn_global_load_lds(AS1(xp + 256 + (lane & 15) * 4), AS3(sh_xf + 256), 16, 0, 0);
            issueOne();
            asm volatile("s_waitcnt vmcnt(10)" ::: "memory");
            __builtin_amdgcn_sched_barrier(0);
        }
        CH_M(0, sh_h1, 4);
        DWRITE(sh_d1, s1r);
        // -------- W2: chunks 21-22 --------
        d0 = zero4(); d1v = zero4();
        TOP(10); CH_M(32768, sh_d1, 0);
        TOP(8);  CH_M(65536, sh_d1, 4);
        DWRITE(sh_d2, s2r);
        // -------- W3 + loss: chunk 23 --------
        TOP(8);
        if (w < 2) {
            f32x4 lacc = zero4();
            #pragma unroll
            for (int s = 0; s < 4; ++s) {
                const lx2 p = PAIRV(98304, s * 2 + w);
                lacc = MFMA8(AF(sh_d2, 2 * s),     p.x, lacc);
                lacc = MFMA8(AF(sh_d2, 2 * s + 1), p.y, lacc);
            }
            const int col = w * 16 + l16;
            if (col < YDIM) {
                #pragma unroll
                for (int q = 0; q < 4; ++q) {
                    const float e = (lacc[q] + s3r) - sh_xf[(kq * 4 + q) * YDIM + col];
                    loss += e * e;
                }
            }
        }
        if (tid < BS * YDIM) sh_x[xr][xc] = f2f8(sh_xf[tid]);   // x(t+1) fp8 (published next TOP)
    }

    asm volatile("s_waitcnt vmcnt(0)" ::: "memory");
    #pragma unroll
    for (int s = 32; s > 0; s >>= 1) loss += __shfl_down(loss, s, 64);
    if (lane == 0 && w < 2) atomicAdd(out, loss);
}

extern "C" void kernel_launch(void* const* d_in, const int* in_sizes, int n_in,
                              void* d_out, int out_size, void* d_ws, size_t ws_size,
                              hipStream_t stream) {
    const float* data = (const float*)d_in[0];
    const float* Wih0 = (const float*)d_in[1];
    const float* Whh0 = (const float*)d_in[2];
    const float* bih0 = (const float*)d_in[3];
    const float* bhh0 = (const float*)d_in[4];
    const float* Wih1 = (const float*)d_in[5];
    const float* Whh1 = (const float*)d_in[6];
    const float* bih1 = (const float*)d_in[7];
    const float* bhh1 = (const float*)d_in[8];
    const float* W1   = (const float*)d_in[9];
    const float* b1   = (const float*)d_in[10];
    const float* W2   = (const float*)d_in[11];
    const float* b2   = (const float*)d_in[12];
    const float* W3   = (const float*)d_in[13];
    const float* b3   = (const float*)d_in[14];
    u16*   ws  = (u16*)d_ws;
    float* out = (float*)d_out;

    hipLaunchKernelGGL(prep_kernel, dim3(512), dim3(256), 0, stream,
                       Wih0, Whh0, Wih1, Whh1, W1, W2, W3, ws, out);
    hipLaunchKernelGGL(rnn_main, dim3(NWG), dim3(512), 0, stream,
                       data, bih0, bhh0, bih1, bhh1, b1, b2, b3, ws, out);
}

// Round 10
// 4261.008 us; speedup vs baseline: 2.9251x; 1.0725x over previous
//
#include <hip/hip_runtime.h>
#include <stdint.h>

typedef __attribute__((ext_vector_type(4))) float f32x4;
typedef __attribute__((ext_vector_type(2))) long lx2;
typedef unsigned short u16;
typedef unsigned char u8;

#define MFMA8(a,b,c) __builtin_amdgcn_mfma_f32_16x16x32_fp8_fp8((a),(b),(c),0,0,0)
#define AS1(p) ((const __attribute__((address_space(1))) void*)(p))
#define AS3(p) ((__attribute__((address_space(3))) void*)(p))

static constexpr int T_STEPS = 256;
static constexpr int BATCH   = 2048;
static constexpr int YDIM    = 20;
static constexpr int BS      = 16;
static constexpr int NWG     = BATCH / BS;        // 128

// fp8 stream: 768 pairs x 1KB = 24 chunks x 32KB (layout as R9, W3 region fixed).
// Pair P, lane L, half h, j: byte P*1024 + L*16 + h*8 + j = W[row][k] fp8,
// k = kb*32 + (L>>4)*8 + j. Consuming wave = P mod 8 for ALL pairs (incl. W3 now).
static constexpr int NPAIR   = 768;
static constexpr int WS_U16  = NPAIR * 512;       // 768 KB

__device__ __forceinline__ float sigm(float x) { return 1.0f / (1.0f + __expf(-x)); }
__device__ __forceinline__ float tanh_fast(float x) {
    float s = __expf(-2.0f * fabsf(x));
    float r = (1.0f - s) / (1.0f + s);
    return copysignf(r, x);
}
__device__ __forceinline__ f32x4 zero4() { f32x4 v = {0.f,0.f,0.f,0.f}; return v; }
__device__ __forceinline__ u8 f2f8(float v) {
    return (u8)(__builtin_amdgcn_cvt_pk_fp8_f32(v, v, 0, false) & 0xff);
}

__device__ float sval(int P, int half, int l16, int k8,
                      const float* __restrict__ Wih0, const float* __restrict__ Whh0,
                      const float* __restrict__ Wih1, const float* __restrict__ Whh1,
                      const float* __restrict__ W1,   const float* __restrict__ W2,
                      const float* __restrict__ W3) {
    if (P < 192) { int kb=P/24, r=P%24, g=r>>3, wv=r&7, c=wv+8*half;
        return Whh0[(g*256 + c*16 + l16)*256 + kb*32 + k8]; }
    if (P < 224) { int r=P-192; if (r>=24) return 0.f;
        int g=r>>3, wv=r&7, c=wv+8*half, row=g*256+c*16+l16;
        return (k8 < YDIM) ? Wih0[row*YDIM + k8] : 0.f; }
    if (P < 416) { int r=P-224, kb=r/24, rr=r%24, g=rr>>3, wv=rr&7, c=wv+8*half;
        return Whh1[(g*256 + c*16 + l16)*256 + kb*32 + k8]; }
    if (P < 608) { int r=P-416, kb=r/24, rr=r%24, g=rr>>3, wv=rr&7, c=wv+8*half;
        return Wih1[(g*256 + c*16 + l16)*256 + kb*32 + k8]; }
    if (P < 672) { int r=P-608, kb=r>>3, wv=r&7, row=(wv+8*half)*16+l16;
        return W1[row*256 + kb*32 + k8]; }
    if (P < 736) { int r=P-672, kb=r>>3, wv=r&7, row=(wv+8*half)*16+l16;
        return W2[row*256 + kb*32 + k8]; }
    // W3: pair P = 736 + s*8 + wv (s=0..3, wv=0..1): half h -> kb = 2s+h, col-tile wv
    { int r=P-736, s=r>>3, wv=r&7;
      if (wv < 2) { int kb = 2*s + half, row = wv*16 + l16;
          return (row < YDIM) ? W3[row*256 + kb*32 + k8] : 0.f; }
      return 0.f; }
}

__global__ void prep_kernel(const float* __restrict__ Wih0, const float* __restrict__ Whh0,
                            const float* __restrict__ Wih1, const float* __restrict__ Whh1,
                            const float* __restrict__ W1,   const float* __restrict__ W2,
                            const float* __restrict__ W3,   u16* __restrict__ ws,
                            float* __restrict__ out) {
    int tid = blockIdx.x * blockDim.x + threadIdx.x;
    if (tid == 0) out[0] = 0.0f;
    int stride = gridDim.x * blockDim.x;
    for (int m = tid; m < WS_U16; m += stride) {
        int byte0 = 2 * m;
        int P = byte0 >> 10, rem = byte0 & 1023;
        int L = rem >> 4, half = (rem >> 3) & 1, j0 = rem & 7;
        int l16 = L & 15, kqb = (L >> 4) * 8;
        float v0 = sval(P, half, l16, kqb + j0,     Wih0, Whh0, Wih1, Whh1, W1, W2, W3);
        float v1 = sval(P, half, l16, kqb + j0 + 1, Wih0, Whh0, Wih1, Whh1, W1, W2, W3);
        ws[m] = (u16)(__builtin_amdgcn_cvt_pk_fp8_f32(v0, v1, 0, false) & 0xffff);
    }
}

// top: publish-drain, barrier, wait own stream; issue happens at END of top
#define TOPB(VMN) do {                                              \
    asm volatile("s_waitcnt lgkmcnt(0)" ::: "memory");              \
    __builtin_amdgcn_sched_barrier(0);                              \
    __builtin_amdgcn_s_barrier();                                   \
    asm volatile("s_waitcnt vmcnt(" #VMN ")" ::: "memory");         \
    __builtin_amdgcn_sched_barrier(0);                              \
} while (0)
#define ISSUE2(CA, CB) do { __builtin_amdgcn_sched_barrier(0); issueChunk(CA); issueChunk(CB); } while (0)
#define ISSUE1(CA)     do { __builtin_amdgcn_sched_barrier(0); issueChunk(CA); } while (0)

#define PAIRV(CSB, P) (*(const lx2*)&ring[(CSB) + (P) * 1024 + lane * 16])
#define AF(S, KT)     (*(const long*)&(S)[l16][(KT) * 32 + kq8])
#define GM2(ACC, A, PV) do { ACC[0] = MFMA8((A), (PV).x, ACC[0]); \
                             ACC[1] = MFMA8((A), (PV).y, ACC[1]); } while (0)
#define CH_A(CSB, S, KB, AN) do {                                                       \
    const long a0_ = AF(S, KB), a1_ = AF(S, (KB)+1);                                    \
    const lx2 p0_=PAIRV(CSB,w), p1_=PAIRV(CSB,8+w), p2_=PAIRV(CSB,16+w), p3_=PAIRV(CSB,24+w); \
    GM2(aR, a0_, p0_); GM2(aZ, a0_, p1_); GM2(AN, a0_, p2_); GM2(aR, a1_, p3_);         \
} while (0)
#define CH_B(CSB, S, KB, AN) do {                                                       \
    const long a0_ = AF(S, KB), a1_ = AF(S, (KB)+1);                                    \
    const lx2 p0_=PAIRV(CSB,w), p1_=PAIRV(CSB,8+w), p2_=PAIRV(CSB,16+w), p3_=PAIRV(CSB,24+w); \
    GM2(aZ, a0_, p0_); GM2(AN, a0_, p1_); GM2(aR, a1_, p2_); GM2(aZ, a1_, p3_);         \
} while (0)
#define CH_C(CSB, S, KB, AN) do {                                                       \
    const long a0_ = AF(S, KB), a1_ = AF(S, (KB)+1);                                    \
    const lx2 p0_=PAIRV(CSB,w), p1_=PAIRV(CSB,8+w), p2_=PAIRV(CSB,16+w), p3_=PAIRV(CSB,24+w); \
    GM2(AN, a0_, p0_); GM2(aR, a1_, p1_); GM2(aZ, a1_, p2_); GM2(AN, a1_, p3_);         \
} while (0)
#define CH_M(CSB, S, KB0) do {                                                          \
    _Pragma("unroll") for (int s_ = 0; s_ < 4; ++s_) {                                  \
        const long a_ = AF(S, (KB0) + s_); const lx2 p_ = PAIRV(CSB, s_ * 8 + w);       \
        d0 = MFMA8(a_, p_.x, d0); d1v = MFMA8(a_, p_.y, d1v); }                         \
} while (0)
#define ZGRU() do { aR[0]=zero4(); aR[1]=zero4(); aZ[0]=zero4(); aZ[1]=zero4();         \
    aXN[0]=zero4(); aXN[1]=zero4(); aHN[0]=zero4(); aHN[1]=zero4(); } while (0)
#define COMBINE(HSH, HR, BR, BZ, BXN, BHN) do {                                         \
    _Pragma("unroll") for (int jj = 0; jj < 2; ++jj) {                                  \
        const int colb_ = (w + 8 * jj) * 16 + l16;                                      \
        _Pragma("unroll") for (int q = 0; q < 4; ++q) {                                 \
            const float r_ = sigm(aR[jj][q] + BR[jj]);                                  \
            const float z_ = sigm(aZ[jj][q] + BZ[jj]);                                  \
            const float n_ = tanh_fast(aXN[jj][q] + BXN[jj] + r_ * (aHN[jj][q] + BHN[jj])); \
            const float hn_ = (1.0f - z_) * n_ + z_ * HR[jj][q];                        \
            HR[jj][q] = hn_;                                                            \
            HSH[kq * 4 + q][colb_] = f2f8(hn_); } }                                     \
} while (0)
#define DWRITE(DSH, SB) do {                                                            \
    _Pragma("unroll") for (int q = 0; q < 4; ++q) {                                     \
        DSH[kq * 4 + q][w * 16 + l16]       = f2f8(fmaxf(d0[q]  + SB[0], 0.f));         \
        DSH[kq * 4 + q][(8 + w) * 16 + l16] = f2f8(fmaxf(d1v[q] + SB[1], 0.f)); }       \
} while (0)

static constexpr int S0 = 0, S1 = 32768, S2 = 65536, S3 = 98304;

__global__ __launch_bounds__(512, 1) void rnn_main(
    const float* __restrict__ data,
    const float* __restrict__ bih0g, const float* __restrict__ bhh0g,
    const float* __restrict__ bih1g, const float* __restrict__ bhh1g,
    const float* __restrict__ b1g,  const float* __restrict__ b2g,
    const float* __restrict__ b3g,
    const u16* __restrict__ ws, float* __restrict__ out)
{
    __shared__ __align__(16) u8 ring[4 * 32768];   // slot = chunk & 3
    __shared__ __align__(16) u8 sh_h0[16][272];
    __shared__ __align__(16) u8 sh_h1[16][272];
    __shared__ __align__(16) u8 sh_d1[16][272];
    __shared__ __align__(16) u8 sh_d2[16][272];
    __shared__ __align__(16) u8 sh_x[16][32];
    __shared__ __align__(16) float sh_xf[512];

    const int tid  = threadIdx.x;
    const int w    = tid >> 6;
    const int lane = tid & 63;
    const int l16  = lane & 15;
    const int kq   = lane >> 4;
    const int kq8  = kq * 8;
    const int b0   = blockIdx.x * BS;
    const int xr   = tid / YDIM, xc = tid - xr * YDIM;

    auto issueChunk = [&](int c) {
        const u8* src = (const u8*)ws + (size_t)c * 32768;
        u8* dst = ring + (size_t)(c & 3) * 32768;
        #pragma unroll
        for (int k = 0; k < 4; ++k)
            __builtin_amdgcn_global_load_lds(AS1(src + k * 8192 + tid * 16),
                                             AS3(dst + k * 8192 + tid * 16), 16, 0, 0);
    };

    for (int i = tid; i < 16 * 272; i += 512) { (&sh_h0[0][0])[i] = 0; (&sh_h1[0][0])[i] = 0; }
    for (int i = tid; i < 16 * 32;  i += 512) (&sh_x[0][0])[i] = 0;
    if (tid < BS * YDIM) sh_x[xr][xc] = f2f8(data[(size_t)b0 * YDIM + tid]);

    float bR0[2], bZ0[2], bXN0[2], bHN0[2], bR1[2], bZ1[2], bXN1[2], bHN1[2], s1r[2], s2r[2];
    #pragma unroll
    for (int jj = 0; jj < 2; ++jj) {
        const int colb = (w + 8 * jj) * 16 + l16;
        bR0[jj]  = bih0g[colb] + bhh0g[colb];
        bZ0[jj]  = bih0g[colb + 256] + bhh0g[colb + 256];
        bXN0[jj] = bih0g[colb + 512];  bHN0[jj] = bhh0g[colb + 512];
        bR1[jj]  = bih1g[colb] + bhh1g[colb];
        bZ1[jj]  = bih1g[colb + 256] + bhh1g[colb + 256];
        bXN1[jj] = bih1g[colb + 512];  bHN1[jj] = bhh1g[colb + 512];
        s1r[jj]  = b1g[colb];  s2r[jj] = b2g[colb];
    }
    float s3r = 0.0f;
    { const int col = w * 16 + l16; if (w < 2 && col < YDIM) s3r = b3g[col]; }

    float hr0[2][4] = {{0,0,0,0},{0,0,0,0}};
    float hr1[2][4] = {{0,0,0,0},{0,0,0,0}};
    f32x4 aR[2], aZ[2], aXN[2], aHN[2], d0, d1v;

    __syncthreads();
    issueChunk(0); issueChunk(1); issueChunk(2); issueChunk(3);
    float loss = 0.0f;

    #pragma unroll 1
    for (int t = 0; t < T_STEPS - 1; ++t) {
        ZGRU();
        // T0: c0,c1 (gh0 kb0-1)
        TOPB(8); CH_A(S0, sh_h0, 0, aHN); CH_B(S1, sh_h0, 1, aHN); ISSUE2(4, 5);
        // T1: c2,c3
        TOPB(8); CH_C(S2, sh_h0, 2, aHN); CH_A(S3, sh_h0, 4, aHN); ISSUE2(6, 7);
        // T2: c4,c5
        TOPB(8); CH_B(S0, sh_h0, 5, aHN); CH_C(S1, sh_h0, 6, aHN); ISSUE2(8, 9);
        // T3: c6 (gx0) + combine0 + c7 (whh1 kb0)
        TOPB(8);
        {
            const long ax = *(const long*)&sh_x[l16][kq8];
            const lx2 p0 = PAIRV(S2, w), p1 = PAIRV(S2, 8 + w), p2 = PAIRV(S2, 16 + w);
            GM2(aR, ax, p0); GM2(aZ, ax, p1); GM2(aXN, ax, p2);
        }
        COMBINE(sh_h0, hr0, bR0, bZ0, bXN0, bHN0);
        ZGRU();
        CH_A(S3, sh_h1, 0, aHN);
        ISSUE2(10, 11);
        // T4: c8,c9 (whh1)
        TOPB(8); CH_B(S0, sh_h1, 1, aHN); CH_C(S1, sh_h1, 2, aHN); ISSUE2(12, 13);
        // T5: c10,c11
        TOPB(8); CH_A(S2, sh_h1, 4, aHN); CH_B(S3, sh_h1, 5, aHN); ISSUE2(14, 15);
        // T6: c12 (whh1 last) + c13 (wih1 first, A = sh_h0 NEW published at T4)
        TOPB(8); CH_C(S0, sh_h1, 6, aHN); CH_A(S1, sh_h0, 0, aXN); ISSUE2(16, 17);
        // T7: c14,c15 (wih1)
        TOPB(8); CH_B(S2, sh_h0, 1, aXN); CH_C(S3, sh_h0, 2, aXN); ISSUE1(18);
        // T8: c16,c17
        TOPB(4); CH_A(S0, sh_h0, 4, aXN); CH_B(S1, sh_h0, 5, aXN); ISSUE2(19, 20);
        // T9: c18 (wih1 last) + combine1
        TOPB(8); CH_C(S2, sh_h0, 6, aXN);
        COMBINE(sh_h1, hr1, bR1, bZ1, bXN1, bHN1);
        ISSUE2(21, 22);
        // T10: c19,c20 (W1) + d1 write; issue c23 + x(t+1)
        TOPB(8);
        d0 = zero4(); d1v = zero4();
        CH_M(S3, sh_h1, 0); CH_M(S0, sh_h1, 4);
        DWRITE(sh_d1, s1r);
        ISSUE1(23);
        {
            const float* xp = data + (size_t)(t + 1) * (BATCH * YDIM) + (size_t)b0 * YDIM;
            __builtin_amdgcn_global_load_lds(AS1(xp + lane * 4), AS3(sh_xf), 16, 0, 0);
            __builtin_amdgcn_global_load_lds(AS1(xp + 256 + (lane & 15) * 4), AS3(sh_xf + 256), 16, 0, 0);
        }
        // T11: c21,c22 (W2) + d2 write; issue next step's c0,c1
        TOPB(6);
        d0 = zero4(); d1v = zero4();
        CH_M(S1, sh_d1, 0); CH_M(S2, sh_d1, 4);
        DWRITE(sh_d2, s2r);
        ISSUE2(0, 1);
        // T12: c23 (W3 + loss, waves 0,1) + x stage; issue next step's c2,c3
        TOPB(8);
        if (w < 2) {
            f32x4 lacc = zero4();
            #pragma unroll
            for (int s = 0; s < 4; ++s) {
                const lx2 p = PAIRV(S3, s * 8 + w);
                lacc = MFMA8(AF(sh_d2, 2 * s),     p.x, lacc);
                lacc = MFMA8(AF(sh_d2, 2 * s + 1), p.y, lacc);
            }
            const int col = w * 16 + l16;
            if (col < YDIM) {
                #pragma unroll
                for (int q = 0; q < 4; ++q) {
                    const float e = (lacc[q] + s3r) - sh_xf[(kq * 4 + q) * YDIM + col];
                    loss += e * e;
                }
            }
        }
        if (tid < BS * YDIM) sh_x[xr][xc] = f2f8(sh_xf[tid]);
        ISSUE2(2, 3);
    }

    asm volatile("s_waitcnt vmcnt(0) lgkmcnt(0)" ::: "memory");
    #pragma unroll
    for (int s = 32; s > 0; s >>= 1) loss += __shfl_down(loss, s, 64);
    if (lane == 0 && w < 2) atomicAdd(out, loss);
}

extern "C" void kernel_launch(void* const* d_in, const int* in_sizes, int n_in,
                              void* d_out, int out_size, void* d_ws, size_t ws_size,
                              hipStream_t stream) {
    const float* data = (const float*)d_in[0];
    const float* Wih0 = (const float*)d_in[1];
    const float* Whh0 = (const float*)d_in[2];
    const float* bih0 = (const float*)d_in[3];
    const float* bhh0 = (const float*)d_in[4];
    const float* Wih1 = (const float*)d_in[5];
    const float* Whh1 = (const float*)d_in[6];
    const float* bih1 = (const float*)d_in[7];
    const float* bhh1 = (const float*)d_in[8];
    const float* W1   = (const float*)d_in[9];
    const float* b1   = (const float*)d_in[10];
    const float* W2   = (const float*)d_in[11];
    const float* b2   = (const float*)d_in[12];
    const float* W3   = (const float*)d_in[13];
    const float* b3   = (const float*)d_in[14];
    u16*   ws  = (u16*)d_ws;
    float* out = (float*)d_out;

    hipLaunchKernelGGL(prep_kernel, dim3(512), dim3(256), 0, stream,
                       Wih0, Whh0, Wih1, Whh1, W1, W2, W3, ws, out);
    hipLaunchKernelGGL(rnn_main, dim3(NWG), dim3(512), 0, stream,
                       data, bih0, bhh0, bih1, bhh1, b1, b2, b3, ws, out);
}

// Round 11
// 2200.918 us; speedup vs baseline: 5.6630x; 1.9360x over previous
//
#include <hip/hip_runtime.h>
#include <stdint.h>

typedef __attribute__((ext_vector_type(4))) float f32x4;
typedef __attribute__((ext_vector_type(2))) long lx2;
typedef unsigned short u16;
typedef unsigned char u8;

#define MFMA8(a,b,c) __builtin_amdgcn_mfma_f32_16x16x32_fp8_fp8((a),(b),(c),0,0,0)

static constexpr int T_STEPS = 256;
static constexpr int BATCH   = 2048;
static constexpr int YDIM    = 20;
static constexpr int BS      = 16;
static constexpr int NWG     = BATCH / BS;        // 128

// fp8 stream layout identical to R10 (proven, absmax 0):
// 768 pairs x 1KB = 24 chunks x 32KB. Pair P, lane L, half h, j:
// byte P*1024 + L*16 + h*8 + j = W[row][k] fp8, k = kb*32 + (L>>4)*8 + j.
// Consuming wave = P mod 8 for ALL pairs.
static constexpr int NPAIR   = 768;
static constexpr int WS_U16  = NPAIR * 512;       // 768 KB

__device__ __forceinline__ float sigm(float x) { return 1.0f / (1.0f + __expf(-x)); }
__device__ __forceinline__ float tanh_fast(float x) {
    float s = __expf(-2.0f * fabsf(x));
    float r = (1.0f - s) / (1.0f + s);
    return copysignf(r, x);
}
__device__ __forceinline__ f32x4 zero4() { f32x4 v = {0.f,0.f,0.f,0.f}; return v; }
__device__ __forceinline__ u8 f2f8(float v) {
    return (u8)(__builtin_amdgcn_cvt_pk_fp8_f32(v, v, 0, false) & 0xff);
}

__device__ float sval(int P, int half, int l16, int k8,
                      const float* __restrict__ Wih0, const float* __restrict__ Whh0,
                      const float* __restrict__ Wih1, const float* __restrict__ Whh1,
                      const float* __restrict__ W1,   const float* __restrict__ W2,
                      const float* __restrict__ W3) {
    if (P < 192) { int kb=P/24, r=P%24, g=r>>3, wv=r&7, c=wv+8*half;
        return Whh0[(g*256 + c*16 + l16)*256 + kb*32 + k8]; }
    if (P < 224) { int r=P-192; if (r>=24) return 0.f;
        int g=r>>3, wv=r&7, c=wv+8*half, row=g*256+c*16+l16;
        return (k8 < YDIM) ? Wih0[row*YDIM + k8] : 0.f; }
    if (P < 416) { int r=P-224, kb=r/24, rr=r%24, g=rr>>3, wv=rr&7, c=wv+8*half;
        return Whh1[(g*256 + c*16 + l16)*256 + kb*32 + k8]; }
    if (P < 608) { int r=P-416, kb=r/24, rr=r%24, g=rr>>3, wv=rr&7, c=wv+8*half;
        return Wih1[(g*256 + c*16 + l16)*256 + kb*32 + k8]; }
    if (P < 672) { int r=P-608, kb=r>>3, wv=r&7, row=(wv+8*half)*16+l16;
        return W1[row*256 + kb*32 + k8]; }
    if (P < 736) { int r=P-672, kb=r>>3, wv=r&7, row=(wv+8*half)*16+l16;
        return W2[row*256 + kb*32 + k8]; }
    { int r=P-736, s=r>>3, wv=r&7;
      if (wv < 2) { int kb = 2*s + half, row = wv*16 + l16;
          return (row < YDIM) ? W3[row*256 + kb*32 + k8] : 0.f; }
      return 0.f; }
}

__global__ void prep_kernel(const float* __restrict__ Wih0, const float* __restrict__ Whh0,
                            const float* __restrict__ Wih1, const float* __restrict__ Whh1,
                            const float* __restrict__ W1,   const float* __restrict__ W2,
                            const float* __restrict__ W3,   u16* __restrict__ ws,
                            float* __restrict__ out) {
    int tid = blockIdx.x * blockDim.x + threadIdx.x;
    if (tid == 0) out[0] = 0.0f;
    int stride = gridDim.x * blockDim.x;
    for (int m = tid; m < WS_U16; m += stride) {
        int byte0 = 2 * m;
        int P = byte0 >> 10, rem = byte0 & 1023;
        int L = rem >> 4, half = (rem >> 3) & 1, j0 = rem & 7;
        int l16 = L & 15, kqb = (L >> 4) * 8;
        float v0 = sval(P, half, l16, kqb + j0,     Wih0, Whh0, Wih1, Whh1, W1, W2, W3);
        float v1 = sval(P, half, l16, kqb + j0 + 1, Wih0, Whh0, Wih1, Whh1, W1, W2, W3);
        ws[m] = (u16)(__builtin_amdgcn_cvt_pk_fp8_f32(v0, v1, 0, false) & 0xffff);
    }
}

#define BARX() do {                                                 \
    asm volatile("s_waitcnt lgkmcnt(0)" ::: "memory");              \
    __builtin_amdgcn_sched_barrier(0);                              \
    __builtin_amdgcn_s_barrier();                                   \
    __builtin_amdgcn_sched_barrier(0);                              \
} while (0)

#define GM2(ACC, A, PV) do { ACC[0] = MFMA8((A), (PV).x, ACC[0]);   \
                             ACC[1] = MFMA8((A), (PV).y, ACC[1]); } while (0)
#define AFB(S, KT) (*(const long*)&(S)[l16][(KT) * 32 + kq8])
// load one chunk's 4 pairs (this wave's) into named regs
#define LOADC(R0, R1, R2, R3, C) do {                               \
    const u8* b_ = wsl + (size_t)(C) * 32768 + woff;                \
    R0 = *(const lx2*)(b_);          R1 = *(const lx2*)(b_ + 8192); \
    R2 = *(const lx2*)(b_ + 16384); R3 = *(const lx2*)(b_ + 24576); \
} while (0)
// chunk MFMA patterns (R10-verified gate interleave)
#define XCH_A(P0,P1,P2,P3, S, KB, AR,AZ,AN) do {                    \
    const long a0_ = AFB(S, KB), a1_ = AFB(S, (KB)+1);              \
    GM2(AR,a0_,P0); GM2(AZ,a0_,P1); GM2(AN,a0_,P2); GM2(AR,a1_,P3); } while (0)
#define XCH_B(P0,P1,P2,P3, S, KB, AR,AZ,AN) do {                    \
    const long a0_ = AFB(S, KB), a1_ = AFB(S, (KB)+1);              \
    GM2(AZ,a0_,P0); GM2(AN,a0_,P1); GM2(AR,a1_,P2); GM2(AZ,a1_,P3); } while (0)
#define XCH_C(P0,P1,P2,P3, S, KB, AR,AZ,AN) do {                    \
    const long a0_ = AFB(S, KB), a1_ = AFB(S, (KB)+1);              \
    GM2(AN,a0_,P0); GM2(AR,a1_,P1); GM2(AZ,a1_,P2); GM2(AN,a1_,P3); } while (0)
#define XCH_M(P0,P1,P2,P3, S, KB0) do {                             \
    const long m0_ = AFB(S, KB0),     m1_ = AFB(S, (KB0)+1);        \
    const long m2_ = AFB(S, (KB0)+2), m3_ = AFB(S, (KB0)+3);        \
    d0 = MFMA8(m0_, P0.x, d0);  d1v = MFMA8(m0_, P0.y, d1v);        \
    d0 = MFMA8(m1_, P1.x, d0);  d1v = MFMA8(m1_, P1.y, d1v);        \
    d0 = MFMA8(m2_, P2.x, d0);  d1v = MFMA8(m2_, P2.y, d1v);        \
    d0 = MFMA8(m3_, P3.x, d0);  d1v = MFMA8(m3_, P3.y, d1v);        \
} while (0)
#define COMBINE(HSH, HR, BRv, BZv, BXNv, BHNv, AR, AZ, AXN, AHN) do {            \
    _Pragma("unroll") for (int jj = 0; jj < 2; ++jj) {                           \
        const int colb_ = (w + 8 * jj) * 16 + l16;                               \
        _Pragma("unroll") for (int q = 0; q < 4; ++q) {                          \
            const float r_ = sigm(AR[jj][q] + BRv[jj]);                          \
            const float z_ = sigm(AZ[jj][q] + BZv[jj]);                          \
            const float n_ = tanh_fast(AXN[jj][q] + BXNv[jj] + r_ * (AHN[jj][q] + BHNv[jj])); \
            const float hn_ = (1.0f - z_) * n_ + z_ * HR[jj][q];                 \
            HR[jj][q] = hn_;                                                     \
            HSH[kq * 4 + q][colb_] = f2f8(hn_); } }                              \
} while (0)
#define DWRITE(DSH, SB) do {                                                     \
    _Pragma("unroll") for (int q = 0; q < 4; ++q) {                              \
        DSH[kq * 4 + q][w * 16 + l16]       = f2f8(fmaxf(d0[q]  + SB[0], 0.f));  \
        DSH[kq * 4 + q][(8 + w) * 16 + l16] = f2f8(fmaxf(d1v[q] + SB[1], 0.f)); }\
} while (0)
#define ZACC(A) do { A[0] = zero4(); A[1] = zero4(); } while (0)

__global__ __launch_bounds__(512, 1) void rnn_main(
    const float* __restrict__ data,
    const float* __restrict__ bih0g, const float* __restrict__ bhh0g,
    const float* __restrict__ bih1g, const float* __restrict__ bhh1g,
    const float* __restrict__ b1g,  const float* __restrict__ b2g,
    const float* __restrict__ b3g,
    const u16* __restrict__ ws, float* __restrict__ out)
{
    __shared__ __align__(16) u8 sh_h0[2][16][272];   // double-buffered recurrent state
    __shared__ __align__(16) u8 sh_h1[2][16][272];
    __shared__ __align__(16) u8 sh_d1[16][272];
    __shared__ __align__(16) u8 sh_d2[16][272];
    __shared__ __align__(16) u8 sh_x[16][32];

    const int tid  = threadIdx.x;
    const int w    = tid >> 6;
    const int lane = tid & 63;
    const int l16  = lane & 15;
    const int kq   = lane >> 4;
    const int kq8  = kq * 8;
    const int b0   = blockIdx.x * BS;
    const int xr   = tid / YDIM, xc = tid - xr * YDIM;
    const size_t woff = (size_t)w * 1024 + (size_t)lane * 16;

    for (int i = tid; i < 2 * 16 * 272; i += 512) { (&sh_h0[0][0][0])[i] = 0; (&sh_h1[0][0][0])[i] = 0; }
    for (int i = tid; i < 16 * 32;  i += 512) (&sh_x[0][0])[i] = 0;
    if (tid < BS * YDIM) sh_x[xr][xc] = f2f8(data[(size_t)b0 * YDIM + tid]);

    float bR0[2], bZ0[2], bXN0[2], bHN0[2], bR1[2], bZ1[2], bXN1[2], bHN1[2], s1r[2], s2r[2];
    #pragma unroll
    for (int jj = 0; jj < 2; ++jj) {
        const int colb = (w + 8 * jj) * 16 + l16;
        bR0[jj]  = bih0g[colb] + bhh0g[colb];
        bZ0[jj]  = bih0g[colb + 256] + bhh0g[colb + 256];
        bXN0[jj] = bih0g[colb + 512];  bHN0[jj] = bhh0g[colb + 512];
        bR1[jj]  = bih1g[colb] + bhh1g[colb];
        bZ1[jj]  = bih1g[colb + 256] + bhh1g[colb + 256];
        bXN1[jj] = bih1g[colb + 512];  bHN1[jj] = bhh1g[colb + 512];
        s1r[jj]  = b1g[colb];  s2r[jj] = b2g[colb];
    }
    float s3r = 0.0f;
    { const int col = w * 16 + l16; if (w < 2 && col < YDIM) s3r = b3g[col]; }

    float hr0[2][4] = {{0,0,0,0},{0,0,0,0}};
    float hr1[2][4] = {{0,0,0,0},{0,0,0,0}};
    f32x4 r0[2], z0[2], xn0[2], hn0[2];     // GRU0 accums
    f32x4 r1[2], z1[2], xn1[2], hn1[2];     // GRU1 accums
    f32x4 d0, d1v;
    lx2 p00, p01, p02, p03, p10, p11, p12, p13, p20, p21, p22, p23;

    __syncthreads();

    {   // prologue: prime 3-deep register ring (chunks 0,1,2)
        const u8* wsl = (const u8*)ws;
        LOADC(p00, p01, p02, p03, 0);
        LOADC(p10, p11, p12, p13, 1);
        LOADC(p20, p21, p22, p23, 2);
    }
    float loss = 0.0f;

    #pragma unroll 1
    for (int t = 0; t < T_STEPS - 1; ++t) {
        const u8* wsl = (const u8*)ws;
        asm volatile("" : "+s"(wsl));     // defeat LICM: keep stream loads inside the loop
        u8 (*h0o)[272] = sh_h0[t & 1];  u8 (*h0n)[272] = sh_h0[(t & 1) ^ 1];
        u8 (*h1o)[272] = sh_h1[t & 1];  u8 (*h1n)[272] = sh_h1[(t & 1) ^ 1];

        ZACC(r0); ZACC(z0); ZACC(xn0); ZACC(hn0);
        ZACC(r1); ZACC(z1); ZACC(xn1); ZACC(hn1);

        // ===== Phase A: gh0 + gx0 + gh1 (reads h0old, h1old, x) — no barriers =====
        XCH_A(p00,p01,p02,p03, h0o, 0, r0,z0,hn0);  LOADC(p00,p01,p02,p03, 3);
        XCH_B(p10,p11,p12,p13, h0o, 1, r0,z0,hn0);  LOADC(p10,p11,p12,p13, 4);
        XCH_C(p20,p21,p22,p23, h0o, 2, r0,z0,hn0);  LOADC(p20,p21,p22,p23, 5);
        XCH_A(p00,p01,p02,p03, h0o, 4, r0,z0,hn0);  LOADC(p00,p01,p02,p03, 6);
        XCH_B(p10,p11,p12,p13, h0o, 5, r0,z0,hn0);  LOADC(p10,p11,p12,p13, 7);
        XCH_C(p20,p21,p22,p23, h0o, 6, r0,z0,hn0);  LOADC(p20,p21,p22,p23, 8);
        {   // gx0 (chunk 6: 3 pairs used)
            const long ax = *(const long*)&sh_x[l16][kq8];
            GM2(r0, ax, p00); GM2(z0, ax, p01); GM2(xn0, ax, p02);
        }
        LOADC(p00,p01,p02,p03, 9);
        XCH_A(p10,p11,p12,p13, h1o, 0, r1,z1,hn1);  LOADC(p10,p11,p12,p13, 10);
        XCH_B(p20,p21,p22,p23, h1o, 1, r1,z1,hn1);  LOADC(p20,p21,p22,p23, 11);
        XCH_C(p00,p01,p02,p03, h1o, 2, r1,z1,hn1);  LOADC(p00,p01,p02,p03, 12);
        XCH_A(p10,p11,p12,p13, h1o, 4, r1,z1,hn1);  LOADC(p10,p11,p12,p13, 13);
        XCH_B(p20,p21,p22,p23, h1o, 5, r1,z1,hn1);  LOADC(p20,p21,p22,p23, 14);
        XCH_C(p00,p01,p02,p03, h1o, 6, r1,z1,hn1);  LOADC(p00,p01,p02,p03, 15);
        // combine0 -> h0new (other buffer: no WAR with phase A)
        COMBINE(h0n, hr0, bR0, bZ0, bXN0, bHN0, r0, z0, xn0, hn0);
        BARX();                                  // B2: publish h0new
        // ===== Phase C: gx1 = wih1 @ h0new =====
        XCH_A(p10,p11,p12,p13, h0n, 0, r1,z1,xn1);  LOADC(p10,p11,p12,p13, 16);
        XCH_B(p20,p21,p22,p23, h0n, 1, r1,z1,xn1);  LOADC(p20,p21,p22,p23, 17);
        XCH_C(p00,p01,p02,p03, h0n, 2, r1,z1,xn1);  LOADC(p00,p01,p02,p03, 18);
        XCH_A(p10,p11,p12,p13, h0n, 4, r1,z1,xn1);  LOADC(p10,p11,p12,p13, 19);
        XCH_B(p20,p21,p22,p23, h0n, 5, r1,z1,xn1);  LOADC(p20,p21,p22,p23, 20);
        XCH_C(p00,p01,p02,p03, h0n, 6, r1,z1,xn1);  LOADC(p00,p01,p02,p03, 21);
        COMBINE(h1n, hr1, bR1, bZ1, bXN1, bHN1, r1, z1, xn1, hn1);
        BARX();                                  // B3: publish h1new
        // ===== Phase D: W1 (A = h1new); issue x(t+1)/target reg loads =====
        d0 = zero4(); d1v = zero4();
        float xv = 0.f, tg0 = 0.f, tg1 = 0.f, tg2 = 0.f, tg3 = 0.f;
        {
            const float* tp = data + (size_t)(t + 1) * (BATCH * YDIM) + (size_t)b0 * YDIM;
            if (tid < BS * YDIM) xv = tp[tid];
            if (w < 2) {
                const int col = w * 16 + l16;
                if (col < YDIM) {
                    tg0 = tp[(kq * 4 + 0) * YDIM + col];
                    tg1 = tp[(kq * 4 + 1) * YDIM + col];
                    tg2 = tp[(kq * 4 + 2) * YDIM + col];
                    tg3 = tp[(kq * 4 + 3) * YDIM + col];
                }
            }
        }
        XCH_M(p10,p11,p12,p13, h1n, 0);  LOADC(p10,p11,p12,p13, 22);
        XCH_M(p20,p21,p22,p23, h1n, 4);  LOADC(p20,p21,p22,p23, 23);
        DWRITE(sh_d1, s1r);
        BARX();                                  // B4: publish d1
        // ===== Phase E: W2 (A = d1) =====
        d0 = zero4(); d1v = zero4();
        XCH_M(p00,p01,p02,p03, sh_d1, 0);  LOADC(p00,p01,p02,p03, 0);
        XCH_M(p10,p11,p12,p13, sh_d1, 4);  LOADC(p10,p11,p12,p13, 1);
        DWRITE(sh_d2, s2r);
        BARX();                                  // B5: publish d2
        // ===== Phase F: W3 + loss (waves 0,1); stage x(t+1) =====
        if (w < 2) {
            f32x4 lacc = zero4();
            lacc = MFMA8(AFB(sh_d2, 0), p20.x, lacc);
            lacc = MFMA8(AFB(sh_d2, 1), p20.y, lacc);
            lacc = MFMA8(AFB(sh_d2, 2), p21.x, lacc);
            lacc = MFMA8(AFB(sh_d2, 3), p21.y, lacc);
            lacc = MFMA8(AFB(sh_d2, 4), p22.x, lacc);
            lacc = MFMA8(AFB(sh_d2, 5), p22.y, lacc);
            lacc = MFMA8(AFB(sh_d2, 6), p23.x, lacc);
            lacc = MFMA8(AFB(sh_d2, 7), p23.y, lacc);
            const int col = w * 16 + l16;
            if (col < YDIM) {
                const float e0 = lacc[0] + s3r - tg0;
                const float e1 = lacc[1] + s3r - tg1;
                const float e2 = lacc[2] + s3r - tg2;
                const float e3 = lacc[3] + s3r - tg3;
                loss += e0 * e0 + e1 * e1 + e2 * e2 + e3 * e3;
            }
        }
        LOADC(p20,p21,p22,p23, 2);
        if (tid < BS * YDIM) sh_x[xr][xc] = f2f8(xv);
        BARX();                                  // B6: publish x(t+1)
    }

    #pragma unroll
    for (int s = 32; s > 0; s >>= 1) loss += __shfl_down(loss, s, 64);
    if (lane == 0 && w < 2) atomicAdd(out, loss);
}

extern "C" void kernel_launch(void* const* d_in, const int* in_sizes, int n_in,
                              void* d_out, int out_size, void* d_ws, size_t ws_size,
                              hipStream_t stream) {
    const float* data = (const float*)d_in[0];
    const float* Wih0 = (const float*)d_in[1];
    const float* Whh0 = (const float*)d_in[2];
    const float* bih0 = (const float*)d_in[3];
    const float* bhh0 = (const float*)d_in[4];
    const float* Wih1 = (const float*)d_in[5];
    const float* Whh1 = (const float*)d_in[6];
    const float* bih1 = (const float*)d_in[7];
    const float* bhh1 = (const float*)d_in[8];
    const float* W1   = (const float*)d_in[9];
    const float* b1   = (const float*)d_in[10];
    const float* W2   = (const float*)d_in[11];
    const float* b2   = (const float*)d_in[12];
    const float* W3   = (const float*)d_in[13];
    const float* b3   = (const float*)d_in[14];
    u16*   ws  = (u16*)d_ws;
    float* out = (float*)d_out;

    hipLaunchKernelGGL(prep_kernel, dim3(512), dim3(256), 0, stream,
                       Wih0, Whh0, Wih1, Whh1, W1, W2, W3, ws, out);
    hipLaunchKernelGGL(rnn_main, dim3(NWG), dim3(512), 0, stream,
                       data, bih0, bhh0, bih1, bhh1, b1, b2, b3, ws, out);
}